// Round 9
// baseline (544.288 us; speedup 1.0000x reference)
//
#include <hip/hip_runtime.h>

typedef unsigned short u16;
typedef __bf16 bf16x8 __attribute__((ext_vector_type(8)));
typedef float f32x4 __attribute__((ext_vector_type(4)));
typedef u16 u16x8 __attribute__((ext_vector_type(8)));
typedef u16 u16x4 __attribute__((ext_vector_type(4)));

#define MFMA16(a, b, c) __builtin_amdgcn_mfma_f32_16x16x32_bf16(a, b, c, 0, 0, 0)

static constexpr float QSC = 0.18033688011112042f;  // 0.125 * log2(e)

__device__ inline u16 f2bf(float f) {
  union { float f; unsigned u; } x; x.f = f;
  unsigned r = x.u + 0x7FFF + ((x.u >> 16) & 1);  // RNE
  return (u16)(r >> 16);
}
__device__ inline u16 cvt_bf(float f) {  // native, pairs into v_cvt_pk_bf16_f32
  __bf16 h = (__bf16)f; return __builtin_bit_cast(u16, h);
}
__device__ inline bf16x8 ld_frag(const u16* p) {
  return __builtin_bit_cast(bf16x8, *(const u16x8*)p);
}
__device__ inline void dma16(const u16* g, u16* l) {
  __builtin_amdgcn_global_load_lds(
      (const __attribute__((address_space(1))) unsigned*)g,
      (__attribute__((address_space(3))) unsigned*)l, 16, 0, 0);
}

#if __has_builtin(__builtin_amdgcn_exp2f)
#define EXP2(x) __builtin_amdgcn_exp2f(x)
#else
#define EXP2(x) exp2f(x)
#endif

#if __has_builtin(__builtin_amdgcn_sched_barrier)
#define SCHED_FENCE() __builtin_amdgcn_sched_barrier(0)
#else
#define SCHED_FENCE()
#endif

// ---------------------------------------------------------------------------
// Weight transpose-convert: W[k][n] fp32 -> Wt[n][k] bf16. z selects weight.
// ---------------------------------------------------------------------------
__launch_bounds__(256)
__global__ void prep_w(const float* __restrict__ Wq, const float* __restrict__ Wk,
                       const float* __restrict__ Wv, const float* __restrict__ Wo,
                       u16* __restrict__ Wt) {
  __shared__ u16 T[64 * 72];
  const int z = blockIdx.z;
  const float* W = z == 0 ? Wq : z == 1 ? Wk : z == 2 ? Wv : Wo;
  u16* D = Wt + ((size_t)z << 20);
  const int k0 = blockIdx.y * 64, c0 = blockIdx.x * 64;
  const int tid = threadIdx.x;
  const int kr = tid >> 2, cs = (tid & 3) * 16;
  const float* src = W + (size_t)(k0 + kr) * 1024 + c0 + cs;
  float f[16];
#pragma unroll
  for (int i = 0; i < 4; ++i) *(float4*)&f[i * 4] = ((const float4*)src)[i];
#pragma unroll
  for (int i = 0; i < 16; ++i) T[(cs + i) * 72 + kr] = cvt_bf(f[i]);
  __syncthreads();
  const int nn = tid >> 2, ks = (tid & 3) * 16;
  u16* dst = D + (size_t)(c0 + nn) * 1024 + k0 + ks;
  *(u16x8*)dst = *(u16x8*)&T[nn * 72 + ks];
  *(u16x8*)(dst + 8) = *(u16x8*)&T[nn * 72 + ks + 8];
}

// ---------------------------------------------------------------------------
// Input convert: fp32 -> bf16 row-major. z selects tensor (8Mi elems each).
// ---------------------------------------------------------------------------
__launch_bounds__(256)
__global__ void prep_a(const float* __restrict__ q, const float* __restrict__ k,
                       const float* __restrict__ v, u16* __restrict__ dq,
                       u16* __restrict__ dk, u16* __restrict__ dv) {
  const int z = blockIdx.z;
  const float* s = z == 0 ? q : z == 1 ? k : v;
  u16* d = z == 0 ? dq : z == 1 ? dk : dv;
  for (size_t i = blockIdx.x * 256 + threadIdx.x; i < (size_t)1048576; i += 262144) {
    const float* g = s + i * 8;
    float4 f0 = *(const float4*)g, f1 = *(const float4*)(g + 4);
    u16x8 h;
    h[0] = cvt_bf(f0.x); h[1] = cvt_bf(f0.y); h[2] = cvt_bf(f0.z); h[3] = cvt_bf(f0.w);
    h[4] = cvt_bf(f1.x); h[5] = cvt_bf(f1.y); h[6] = cvt_bf(f1.z); h[7] = cvt_bf(f1.w);
    *(u16x8*)(d + i * 8) = h;
  }
}

// ---------------------------------------------------------------------------
// QKV GEMM, m97-style both-sides DMA, XCD-swizzled (m0 per XCD, n cycles fast).
// z=0: Q=relu*QSC token-major; z=1: K token-major; z=2: V -> [bh][d][s].
// ---------------------------------------------------------------------------
__launch_bounds__(256)
__global__ void gemm_fwd(const u16* __restrict__ Aq, const u16* __restrict__ Ak,
                         const u16* __restrict__ Av, const u16* __restrict__ Wt,
                         u16* __restrict__ Qw, u16* __restrict__ Kw,
                         u16* __restrict__ Vw) {
  __shared__ u16 smem[8704];
  u16* Asm = smem;
  u16* Bsm = smem + 4096;
  const int z = blockIdx.z;
  const u16* A = z == 0 ? Aq : z == 1 ? Ak : Av;
  const u16* Bt = Wt + ((size_t)z << 20);
  u16* out = z == 0 ? Qw : z == 1 ? Kw : Vw;

  const int tid = threadIdx.x;
  const int lane = tid & 63, l15 = lane & 15, quad = lane >> 4;
  const int wv = tid >> 6, wm = wv & 1, wn = wv >> 1;
  const int m0 = (blockIdx.x * 8 + (blockIdx.y >> 3)) * 128;
  const int n0 = (blockIdx.y & 7) * 128;

  f32x4 acc[4][4] = {};

  for (int k0 = 0; k0 < 1024; k0 += 32) {
    __syncthreads();
#pragma unroll
    for (int t = 0; t < 2; ++t) {
      const int cb = t * 256 + wv * 64;
      const int c = cb + lane, mn = c & 127, kc = c >> 7;
      dma16(A + (size_t)(m0 + mn) * 1024 + k0 + kc * 8, &Asm[cb * 8]);
      dma16(Bt + (size_t)(n0 + mn) * 1024 + k0 + kc * 8, &Bsm[cb * 8]);
    }
    __syncthreads();
    bf16x8 a[4], b[4];
#pragma unroll
    for (int i = 0; i < 4; ++i)
      a[i] = ld_frag(&Asm[(quad * 128 + wm * 64 + i * 16 + l15) * 8]);
#pragma unroll
    for (int j = 0; j < 4; ++j)
      b[j] = ld_frag(&Bsm[(quad * 128 + wn * 64 + j * 16 + l15) * 8]);
#pragma unroll
    for (int i = 0; i < 4; ++i)
#pragma unroll
      for (int j = 0; j < 4; ++j)
        acc[i][j] = MFMA16(a[i], b[j], acc[i][j]);
  }

  if (z < 2) {
    const float sc = z == 0 ? QSC : 1.0f;
#pragma unroll
    for (int i = 0; i < 4; ++i)
#pragma unroll
      for (int j = 0; j < 4; ++j)
#pragma unroll
        for (int r = 0; r < 4; ++r) {
          float v = fmaxf(acc[i][j][r], 0.f) * sc;
          int m = m0 + wm * 64 + i * 16 + quad * 4 + r;
          int n = n0 + wn * 64 + j * 16 + l15;
          out[(size_t)m * 1024 + n] = f2bf(v);
        }
  } else {
    // V: transpose through LDS -> Vt[bh][d][s]
    const int b = m0 >> 11, s0 = m0 & 2047;
#pragma unroll
    for (int half = 0; half < 2; ++half) {
      __syncthreads();
      if (wn == half) {
#pragma unroll
        for (int i = 0; i < 4; ++i)
#pragma unroll
          for (int j = 0; j < 4; ++j) {
            u16x4 pk;
#pragma unroll
            for (int r = 0; r < 4; ++r) pk[r] = f2bf(fmaxf(acc[i][j][r], 0.f));
            const int nn = j * 16 + l15;
            const int ml = wm * 64 + i * 16 + quad * 4;
            *(u16x4*)&smem[nn * 136 + ml] = pk;
          }
      }
      __syncthreads();
      const int h = (n0 + half * 64) >> 6;
      const int nn = tid >> 2, seg = (tid & 3) * 32;
      u16* dst = out + ((size_t)((b * 16 + h) * 64 + nn)) * 2048 + s0 + seg;
#pragma unroll
      for (int i2 = 0; i2 < 4; ++i2)
        *(u16x8*)&dst[i2 * 8] = *(u16x8*)&smem[nn * 136 + seg + i2 * 8];
    }
  }
}

// ---------------------------------------------------------------------------
// Output GEMM: relu(ctx @ Wo); same XCD swizzle; out fp32.
// ---------------------------------------------------------------------------
__launch_bounds__(256)
__global__ void gemm_out(const u16* __restrict__ A, const u16* __restrict__ Bt,
                         float* __restrict__ out) {
  __shared__ u16 smem[8192];
  u16* Asm = smem;
  u16* Bsm = smem + 4096;
  const int tid = threadIdx.x;
  const int lane = tid & 63, l15 = lane & 15, quad = lane >> 4;
  const int wv = tid >> 6, wm = wv & 1, wn = wv >> 1;
  const int m0 = (blockIdx.x * 8 + (blockIdx.y >> 3)) * 128;
  const int n0 = (blockIdx.y & 7) * 128;
  f32x4 acc[4][4] = {};

  for (int k0 = 0; k0 < 1024; k0 += 32) {
    __syncthreads();
#pragma unroll
    for (int t = 0; t < 2; ++t) {
      const int cb = t * 256 + wv * 64;
      const int c = cb + lane, mn = c & 127, kc = c >> 7;
      dma16(A + (size_t)(m0 + mn) * 1024 + k0 + kc * 8, &Asm[cb * 8]);
      dma16(Bt + (size_t)(n0 + mn) * 1024 + k0 + kc * 8, &Bsm[cb * 8]);
    }
    __syncthreads();
    bf16x8 a[4], b[4];
#pragma unroll
    for (int i = 0; i < 4; ++i)
      a[i] = ld_frag(&Asm[(quad * 128 + wm * 64 + i * 16 + l15) * 8]);
#pragma unroll
    for (int j = 0; j < 4; ++j)
      b[j] = ld_frag(&Bsm[(quad * 128 + wn * 64 + j * 16 + l15) * 8]);
#pragma unroll
    for (int i = 0; i < 4; ++i)
#pragma unroll
      for (int j = 0; j < 4; ++j)
        acc[i][j] = MFMA16(a[i], b[j], acc[i][j]);
  }
#pragma unroll
  for (int i = 0; i < 4; ++i)
#pragma unroll
    for (int j = 0; j < 4; ++j)
#pragma unroll
      for (int r = 0; r < 4; ++r) {
        int m = m0 + wm * 64 + i * 16 + quad * 4 + r;
        int n = n0 + wn * 64 + j * 16 + l15;
        out[(size_t)m * 1024 + n] = fmaxf(acc[i][j][r], 0.f);
      }
}

// ---------------------------------------------------------------------------
// Flash attention v7 — single-wave blocks + sched_barrier-pinned load cluster.
// All 16 K/V fragment loads issue back-to-back at tile top (K first, V second;
// in-order vmcnt: QK waits vmcnt(8), V stays in flight through softmax).
// __builtin_amdgcn_sched_barrier(0) prevents the scheduler from re-sinking
// the loads (r7/r8: VGPR=60 proved it serialized them -> ~16 exposed
// round-trips/tile). Grid (bh=64, qb=64) = 16 one-wave blocks/CU.
// ---------------------------------------------------------------------------
__launch_bounds__(64, 3)
__global__ void attn(const u16* __restrict__ Q, const u16* __restrict__ K,
                     const u16* __restrict__ V, u16* __restrict__ ctx) {
  __shared__ u16 Pw[2048];  // chunks [kc(8)][q(32)] x 8 u16

  const int lane = threadIdx.x & 63;
  const int l15 = lane & 15, quad = lane >> 4;
  const int bh = blockIdx.x, b = bh >> 4, h = bh & 15;
  const int q0 = blockIdx.y * 32;

  const u16* Kb = K + ((size_t)b * 2048) * 1024 + h * 64;
  const u16* Vb = V + (size_t)bh * 64 * 2048;

  // Q B-frags (pre-scaled by 0.125*log2e), resident all kernel
  bf16x8 aq[2][2];
#pragma unroll
  for (int qh = 0; qh < 2; ++qh)
#pragma unroll
    for (int kk = 0; kk < 2; ++kk)
      aq[qh][kk] = ld_frag(Q + (size_t)(b * 2048 + q0 + qh * 16 + l15) * 1024 +
                           h * 64 + kk * 32 + quad * 8);

  f32x4 o[2][4] = {};
  float ls[2] = {0.f, 0.f};

#pragma unroll 1
  for (int t = 0; t < 32; ++t) {
    const int k0 = t * 64;

    // --- load cluster: 8 K frags then 8 V frags, pinned by sched_barrier ---
    bf16x8 kf[2][4];
#pragma unroll
    for (int kk = 0; kk < 2; ++kk)
#pragma unroll
      for (int jj = 0; jj < 4; ++jj)
        kf[kk][jj] = ld_frag(Kb + (size_t)(k0 + jj * 16 + l15) * 1024 +
                             kk * 32 + quad * 8);
    bf16x8 vf[2][4];
#pragma unroll
    for (int kk = 0; kk < 2; ++kk)
#pragma unroll
      for (int j = 0; j < 4; ++j)
        vf[kk][j] = ld_frag(Vb + (size_t)(j * 16 + l15) * 2048 + k0 +
                            kk * 32 + quad * 8);
    SCHED_FENCE();  // nothing crosses: loads cannot sink below this point

    // S^T = K·Q^T (col = q = l15, row = key = quad*4+r within 16-block jj)
    f32x4 st[2][4] = {};
#pragma unroll
    for (int kk = 0; kk < 2; ++kk)
#pragma unroll
      for (int jj = 0; jj < 4; ++jj)
#pragma unroll
        for (int qh = 0; qh < 2; ++qh)
          st[qh][jj] = MFMA16(kf[kk][jj], aq[qh][kk], st[qh][jj]);

    // p = exp2(st); packed cvt; chunked conflict-free P write
#pragma unroll
    for (int qh = 0; qh < 2; ++qh)
#pragma unroll
      for (int jj = 0; jj < 4; ++jj) {
        float p0 = EXP2(st[qh][jj][0]), p1 = EXP2(st[qh][jj][1]);
        float p2 = EXP2(st[qh][jj][2]), p3 = EXP2(st[qh][jj][3]);
        ls[qh] += (p0 + p1) + (p2 + p3);
        u16x4 pk;
        pk[0] = cvt_bf(p0); pk[1] = cvt_bf(p1);
        pk[2] = cvt_bf(p2); pk[3] = cvt_bf(p3);
        const int kc = jj * 2 + (quad >> 1);
        *(u16x4*)&Pw[(kc * 32 + qh * 16 + l15) * 8 + (quad & 1) * 4] = pk;
      }

    // all 4 pa ds_reads grouped (one exposed DS latency, not four)
    bf16x8 pa[2][2];
#pragma unroll
    for (int kk = 0; kk < 2; ++kk)
#pragma unroll
      for (int qh = 0; qh < 2; ++qh)
        pa[kk][qh] = ld_frag(&Pw[((kk * 4 + quad) * 32 + qh * 16 + l15) * 8]);

    // O^T += V^T · P^T (vf in flight since tile top; drained here by scoreboard)
#pragma unroll
    for (int kk = 0; kk < 2; ++kk)
#pragma unroll
      for (int j = 0; j < 4; ++j)
#pragma unroll
        for (int qh = 0; qh < 2; ++qh)
          o[qh][j] = MFMA16(vf[kk][j], pa[kk][qh], o[qh][j]);
  }

  float inv[2];
#pragma unroll
  for (int qh = 0; qh < 2; ++qh) {
    ls[qh] += __shfl_xor(ls[qh], 16, 64);
    ls[qh] += __shfl_xor(ls[qh], 32, 64);
    inv[qh] = 1.f / ls[qh];
  }

  // O^T: row = d = j*16+quad*4+r, col = q = l15 -> 8B vector ctx stores
#pragma unroll
  for (int qh = 0; qh < 2; ++qh) {
    const int tok = b * 2048 + q0 + qh * 16 + l15;
#pragma unroll
    for (int j = 0; j < 4; ++j) {
      u16x4 pk;
#pragma unroll
      for (int r = 0; r < 4; ++r) pk[r] = cvt_bf(o[qh][j][r] * inv[qh]);
      *(u16x4*)&ctx[(size_t)tok * 1024 + h * 64 + j * 16 + quad * 4] = pk;
    }
  }
}

// ---------------------------------------------------------------------------
extern "C" void kernel_launch(void* const* d_in, const int* in_sizes, int n_in,
                              void* d_out, int out_size, void* d_ws, size_t ws_size,
                              hipStream_t stream) {
  const float* query = (const float*)d_in[0];
  const float* key   = (const float*)d_in[1];
  const float* value = (const float*)d_in[2];
  const float* Wq = (const float*)d_in[3];
  const float* Wk = (const float*)d_in[4];
  const float* Wv = (const float*)d_in[5];
  const float* Wo = (const float*)d_in[6];
  float* outp = (float*)d_out;

  // ws (u16 units): Wt 4Mi | Awq 8Mi | Qw 8Mi | Kw 8Mi | Vt 8Mi = 72 MB.
  // Awk/Awv live in d_out (32 MB, consumed before gemm_out overwrites it);
  // ctx aliases Awq (consumed by gemm_fwd before attn writes it).
  u16* Wt  = (u16*)d_ws;
  u16* Awq = Wt + ((size_t)4 << 20);
  u16* Qw  = Awq + ((size_t)8 << 20);
  u16* Kw  = Qw + ((size_t)8 << 20);
  u16* Vt  = Kw + ((size_t)8 << 20);
  u16* Awk = (u16*)d_out;
  u16* Awv = Awk + ((size_t)8 << 20);
  u16* Cw  = Awq;

  prep_w<<<dim3(16, 16, 4), 256, 0, stream>>>(Wq, Wk, Wv, Wo, Wt);
  prep_a<<<dim3(1024, 1, 3), 256, 0, stream>>>(query, key, value, Awq, Awk, Awv);
  gemm_fwd<<<dim3(8, 64, 3), 256, 0, stream>>>(Awq, Awk, Awv, Wt, Qw, Kw, Vt);
  attn<<<dim3(64, 64), 64, 0, stream>>>(Qw, Kw, Vt, Cw);
  gemm_out<<<dim3(8, 64), 256, 0, stream>>>(Cw, Wt + ((size_t)3 << 20), outp);
}

// Round 10
// 401.373 us; speedup vs baseline: 1.3561x; 1.3561x over previous
//
#include <hip/hip_runtime.h>

typedef unsigned short u16;
typedef __bf16 bf16x8 __attribute__((ext_vector_type(8)));
typedef float f32x4 __attribute__((ext_vector_type(4)));
typedef u16 u16x8 __attribute__((ext_vector_type(8)));
typedef u16 u16x4 __attribute__((ext_vector_type(4)));

#define MFMA16(a, b, c) __builtin_amdgcn_mfma_f32_16x16x32_bf16(a, b, c, 0, 0, 0)

static constexpr float QSC = 0.18033688011112042f;  // 0.125 * log2(e)

__device__ inline u16 f2bf(float f) {
  union { float f; unsigned u; } x; x.f = f;
  unsigned r = x.u + 0x7FFF + ((x.u >> 16) & 1);  // RNE
  return (u16)(r >> 16);
}
__device__ inline u16 cvt_bf(float f) {  // native, pairs into v_cvt_pk_bf16_f32
  __bf16 h = (__bf16)f; return __builtin_bit_cast(u16, h);
}
__device__ inline bf16x8 ld_frag(const u16* p) {
  return __builtin_bit_cast(bf16x8, *(const u16x8*)p);
}
__device__ inline void dma16(const u16* g, u16* l) {
  __builtin_amdgcn_global_load_lds(
      (const __attribute__((address_space(1))) unsigned*)g,
      (__attribute__((address_space(3))) unsigned*)l, 16, 0, 0);
}

#if __has_builtin(__builtin_amdgcn_exp2f)
#define EXP2(x) __builtin_amdgcn_exp2f(x)
#else
#define EXP2(x) exp2f(x)
#endif

// ---------------------------------------------------------------------------
// Weight transpose-convert: W[k][n] fp32 -> Wt[n][k] bf16. z selects weight.
// ---------------------------------------------------------------------------
__launch_bounds__(256)
__global__ void prep_w(const float* __restrict__ Wq, const float* __restrict__ Wk,
                       const float* __restrict__ Wv, const float* __restrict__ Wo,
                       u16* __restrict__ Wt) {
  __shared__ u16 T[64 * 72];
  const int z = blockIdx.z;
  const float* W = z == 0 ? Wq : z == 1 ? Wk : z == 2 ? Wv : Wo;
  u16* D = Wt + ((size_t)z << 20);
  const int k0 = blockIdx.y * 64, c0 = blockIdx.x * 64;
  const int tid = threadIdx.x;
  const int kr = tid >> 2, cs = (tid & 3) * 16;
  const float* src = W + (size_t)(k0 + kr) * 1024 + c0 + cs;
  float f[16];
#pragma unroll
  for (int i = 0; i < 4; ++i) *(float4*)&f[i * 4] = ((const float4*)src)[i];
#pragma unroll
  for (int i = 0; i < 16; ++i) T[(cs + i) * 72 + kr] = cvt_bf(f[i]);
  __syncthreads();
  const int nn = tid >> 2, ks = (tid & 3) * 16;
  u16* dst = D + (size_t)(c0 + nn) * 1024 + k0 + ks;
  *(u16x8*)dst = *(u16x8*)&T[nn * 72 + ks];
  *(u16x8*)(dst + 8) = *(u16x8*)&T[nn * 72 + ks + 8];
}

// ---------------------------------------------------------------------------
// Input convert: fp32 -> bf16 row-major. z selects tensor (8Mi elems each).
// ---------------------------------------------------------------------------
__launch_bounds__(256)
__global__ void prep_a(const float* __restrict__ q, const float* __restrict__ k,
                       const float* __restrict__ v, u16* __restrict__ dq,
                       u16* __restrict__ dk, u16* __restrict__ dv) {
  const int z = blockIdx.z;
  const float* s = z == 0 ? q : z == 1 ? k : v;
  u16* d = z == 0 ? dq : z == 1 ? dk : dv;
  for (size_t i = blockIdx.x * 256 + threadIdx.x; i < (size_t)1048576; i += 262144) {
    const float* g = s + i * 8;
    float4 f0 = *(const float4*)g, f1 = *(const float4*)(g + 4);
    u16x8 h;
    h[0] = cvt_bf(f0.x); h[1] = cvt_bf(f0.y); h[2] = cvt_bf(f0.z); h[3] = cvt_bf(f0.w);
    h[4] = cvt_bf(f1.x); h[5] = cvt_bf(f1.y); h[6] = cvt_bf(f1.z); h[7] = cvt_bf(f1.w);
    *(u16x8*)(d + i * 8) = h;
  }
}

// ---------------------------------------------------------------------------
// QKV GEMM, m97-style both-sides DMA, XCD-swizzled (m0 per XCD, n cycles fast).
// z=0: Q=relu*QSC token-major; z=1: K token-major; z=2: V -> [bh][d][s].
// ---------------------------------------------------------------------------
__launch_bounds__(256)
__global__ void gemm_fwd(const u16* __restrict__ Aq, const u16* __restrict__ Ak,
                         const u16* __restrict__ Av, const u16* __restrict__ Wt,
                         u16* __restrict__ Qw, u16* __restrict__ Kw,
                         u16* __restrict__ Vw) {
  __shared__ u16 smem[8704];
  u16* Asm = smem;
  u16* Bsm = smem + 4096;
  const int z = blockIdx.z;
  const u16* A = z == 0 ? Aq : z == 1 ? Ak : Av;
  const u16* Bt = Wt + ((size_t)z << 20);
  u16* out = z == 0 ? Qw : z == 1 ? Kw : Vw;

  const int tid = threadIdx.x;
  const int lane = tid & 63, l15 = lane & 15, quad = lane >> 4;
  const int wv = tid >> 6, wm = wv & 1, wn = wv >> 1;
  const int m0 = (blockIdx.x * 8 + (blockIdx.y >> 3)) * 128;
  const int n0 = (blockIdx.y & 7) * 128;

  f32x4 acc[4][4] = {};

  for (int k0 = 0; k0 < 1024; k0 += 32) {
    __syncthreads();
#pragma unroll
    for (int t = 0; t < 2; ++t) {
      const int cb = t * 256 + wv * 64;
      const int c = cb + lane, mn = c & 127, kc = c >> 7;
      dma16(A + (size_t)(m0 + mn) * 1024 + k0 + kc * 8, &Asm[cb * 8]);
      dma16(Bt + (size_t)(n0 + mn) * 1024 + k0 + kc * 8, &Bsm[cb * 8]);
    }
    __syncthreads();
    bf16x8 a[4], b[4];
#pragma unroll
    for (int i = 0; i < 4; ++i)
      a[i] = ld_frag(&Asm[(quad * 128 + wm * 64 + i * 16 + l15) * 8]);
#pragma unroll
    for (int j = 0; j < 4; ++j)
      b[j] = ld_frag(&Bsm[(quad * 128 + wn * 64 + j * 16 + l15) * 8]);
#pragma unroll
    for (int i = 0; i < 4; ++i)
#pragma unroll
      for (int j = 0; j < 4; ++j)
        acc[i][j] = MFMA16(a[i], b[j], acc[i][j]);
  }

  if (z < 2) {
    const float sc = z == 0 ? QSC : 1.0f;
#pragma unroll
    for (int i = 0; i < 4; ++i)
#pragma unroll
      for (int j = 0; j < 4; ++j)
#pragma unroll
        for (int r = 0; r < 4; ++r) {
          float v = fmaxf(acc[i][j][r], 0.f) * sc;
          int m = m0 + wm * 64 + i * 16 + quad * 4 + r;
          int n = n0 + wn * 64 + j * 16 + l15;
          out[(size_t)m * 1024 + n] = f2bf(v);
        }
  } else {
    // V: transpose through LDS -> Vt[bh][d][s]
    const int b = m0 >> 11, s0 = m0 & 2047;
#pragma unroll
    for (int half = 0; half < 2; ++half) {
      __syncthreads();
      if (wn == half) {
#pragma unroll
        for (int i = 0; i < 4; ++i)
#pragma unroll
          for (int j = 0; j < 4; ++j) {
            u16x4 pk;
#pragma unroll
            for (int r = 0; r < 4; ++r) pk[r] = f2bf(fmaxf(acc[i][j][r], 0.f));
            const int nn = j * 16 + l15;
            const int ml = wm * 64 + i * 16 + quad * 4;
            *(u16x4*)&smem[nn * 136 + ml] = pk;
          }
      }
      __syncthreads();
      const int h = (n0 + half * 64) >> 6;
      const int nn = tid >> 2, seg = (tid & 3) * 32;
      u16* dst = out + ((size_t)((b * 16 + h) * 64 + nn)) * 2048 + s0 + seg;
#pragma unroll
      for (int i2 = 0; i2 < 4; ++i2)
        *(u16x8*)&dst[i2 * 8] = *(u16x8*)&smem[nn * 136 + seg + i2 * 8];
    }
  }
}

// ---------------------------------------------------------------------------
// Output GEMM: relu(ctx @ Wo); same XCD swizzle; out fp32.
// ---------------------------------------------------------------------------
__launch_bounds__(256)
__global__ void gemm_out(const u16* __restrict__ A, const u16* __restrict__ Bt,
                         float* __restrict__ out) {
  __shared__ u16 smem[8192];
  u16* Asm = smem;
  u16* Bsm = smem + 4096;
  const int tid = threadIdx.x;
  const int lane = tid & 63, l15 = lane & 15, quad = lane >> 4;
  const int wv = tid >> 6, wm = wv & 1, wn = wv >> 1;
  const int m0 = (blockIdx.x * 8 + (blockIdx.y >> 3)) * 128;
  const int n0 = (blockIdx.y & 7) * 128;
  f32x4 acc[4][4] = {};

  for (int k0 = 0; k0 < 1024; k0 += 32) {
    __syncthreads();
#pragma unroll
    for (int t = 0; t < 2; ++t) {
      const int cb = t * 256 + wv * 64;
      const int c = cb + lane, mn = c & 127, kc = c >> 7;
      dma16(A + (size_t)(m0 + mn) * 1024 + k0 + kc * 8, &Asm[cb * 8]);
      dma16(Bt + (size_t)(n0 + mn) * 1024 + k0 + kc * 8, &Bsm[cb * 8]);
    }
    __syncthreads();
    bf16x8 a[4], b[4];
#pragma unroll
    for (int i = 0; i < 4; ++i)
      a[i] = ld_frag(&Asm[(quad * 128 + wm * 64 + i * 16 + l15) * 8]);
#pragma unroll
    for (int j = 0; j < 4; ++j)
      b[j] = ld_frag(&Bsm[(quad * 128 + wn * 64 + j * 16 + l15) * 8]);
#pragma unroll
    for (int i = 0; i < 4; ++i)
#pragma unroll
      for (int j = 0; j < 4; ++j)
        acc[i][j] = MFMA16(a[i], b[j], acc[i][j]);
  }
#pragma unroll
  for (int i = 0; i < 4; ++i)
#pragma unroll
    for (int j = 0; j < 4; ++j)
#pragma unroll
      for (int r = 0; r < 4; ++r) {
        int m = m0 + wm * 64 + i * 16 + quad * 4 + r;
        int n = n0 + wn * 64 + j * 16 + l15;
        out[(size_t)m * 1024 + n] = fmaxf(acc[i][j][r], 0.f);
      }
}

// ---------------------------------------------------------------------------
// Flash attention v8 — fully DMA-staged K+V, DOUBLE-BUFFERED, 1 barrier/tile.
// 64-key tiles; DMA issued at tile t top is consumed at tile t+1 (full tile of
// slack -> barrier's vmcnt(0) drain finds data landed). All operand reads are
// LDS b128 in verified chunk layouts: Ksm/Vsm [chunk8][6416-lane], P per-wave.
// 128 q/block (4 waves x 32 q). LDS 48KB -> 3 blocks/CU.
// ---------------------------------------------------------------------------
__launch_bounds__(256, 3)
__global__ void attn(const u16* __restrict__ Q, const u16* __restrict__ K,
                     const u16* __restrict__ V, u16* __restrict__ ctx) {
  __shared__ u16 Ksm[2][4096];  // chunks [dc(8)][key(64)] x 8 u16 (8KB/buf)
  __shared__ u16 Vsm[2][4096];  // chunks [kc(8)][d(64)]  x 8 u16
  __shared__ u16 Psm[4][2048];  // per-wave chunks [kc(8)][q(32)] x 8 u16

  const int tid = threadIdx.x;
  const int lane = tid & 63, l15 = lane & 15, quad = lane >> 4;
  const int wv = tid >> 6;
  const int bh = blockIdx.x, b = bh >> 4, h = bh & 15;
  const int q0 = blockIdx.y * 128 + wv * 32;

  const u16* Kb = K + ((size_t)b * 2048) * 1024 + h * 64;
  const u16* Vb = V + (size_t)bh * 64 * 2048;
  u16* Pw = Psm[wv];

  // Per-thread DMA sources. Chunk id c = issue*256+tid covers 512 chunks/tensor:
  // K: key = c&63 (row, token-major), dc = c>>6  -> LDS [dc][key]
  // V: d   = c&63 (row, [d][s] layout), kc = c>>6 -> LDS [kc][d]
  const int ck0 = tid, ck1 = 256 + tid;
  const u16* kg0 = Kb + (size_t)(ck0 & 63) * 1024 + (ck0 >> 6) * 8;
  const u16* kg1 = Kb + (size_t)(ck1 & 63) * 1024 + (ck1 >> 6) * 8;
  const u16* vg0 = Vb + (size_t)(ck0 & 63) * 2048 + (ck0 >> 6) * 8;
  const u16* vg1 = Vb + (size_t)(ck1 & 63) * 2048 + (ck1 >> 6) * 8;

  // Q B-frags (pre-scaled by 0.125*log2e), resident all kernel
  bf16x8 aq[2][2];
#pragma unroll
  for (int qh = 0; qh < 2; ++qh)
#pragma unroll
    for (int kk = 0; kk < 2; ++kk)
      aq[qh][kk] = ld_frag(Q + (size_t)(b * 2048 + q0 + qh * 16 + l15) * 1024 +
                           h * 64 + kk * 32 + quad * 8);

  f32x4 o[2][4] = {};
  float ls[2] = {0.f, 0.f};

  // Prologue: DMA tile 0 -> buffer 0
  dma16(kg0, &Ksm[0][ck0 * 8]);
  dma16(kg1, &Ksm[0][ck1 * 8]);
  dma16(vg0, &Vsm[0][ck0 * 8]);
  dma16(vg1, &Vsm[0][ck1 * 8]);

#pragma unroll 1
  for (int t = 0; t < 32; ++t) {
    const int cur = t & 1, nxt = cur ^ 1;
    __syncthreads();  // drains tile-t DMA (vmcnt) + prior tile's LDS reads (WAR)

    if (t + 1 < 32) {  // DMA tile t+1 -> other buffer; consumed after NEXT barrier
      const int kadv = (t + 1) * 64;
      dma16(kg0 + (size_t)kadv * 1024, &Ksm[nxt][ck0 * 8]);
      dma16(kg1 + (size_t)kadv * 1024, &Ksm[nxt][ck1 * 8]);
      dma16(vg0 + kadv, &Vsm[nxt][ck0 * 8]);
      dma16(vg1 + kadv, &Vsm[nxt][ck1 * 8]);
    }

    // kf from LDS: A-frag [m=key=jj*16+l15][k=d=kk*32+quad*8]
    bf16x8 kf[2][4];
#pragma unroll
    for (int kk = 0; kk < 2; ++kk)
#pragma unroll
      for (int jj = 0; jj < 4; ++jj)
        kf[kk][jj] = ld_frag(&Ksm[cur][((kk * 4 + quad) * 64 + jj * 16 + l15) * 8]);

    // S^T = K·Q^T (col = q = l15, row = key = quad*4+r within 16-block jj)
    f32x4 st[2][4] = {};
#pragma unroll
    for (int kk = 0; kk < 2; ++kk)
#pragma unroll
      for (int jj = 0; jj < 4; ++jj)
#pragma unroll
        for (int qh = 0; qh < 2; ++qh)
          st[qh][jj] = MFMA16(kf[kk][jj], aq[qh][kk], st[qh][jj]);

    // p = exp2(st); packed cvt; chunked conflict-free P write
#pragma unroll
    for (int qh = 0; qh < 2; ++qh)
#pragma unroll
      for (int jj = 0; jj < 4; ++jj) {
        float p0 = EXP2(st[qh][jj][0]), p1 = EXP2(st[qh][jj][1]);
        float p2 = EXP2(st[qh][jj][2]), p3 = EXP2(st[qh][jj][3]);
        ls[qh] += (p0 + p1) + (p2 + p3);
        u16x4 pk;
        pk[0] = cvt_bf(p0); pk[1] = cvt_bf(p1);
        pk[2] = cvt_bf(p2); pk[3] = cvt_bf(p3);
        const int kc = jj * 2 + (quad >> 1);
        *(u16x4*)&Pw[(kc * 32 + qh * 16 + l15) * 8 + (quad & 1) * 4] = pk;
      }

    // pa (B-frag of P^T) and vb (A-frag of V^T) from LDS; PV MFMAs
#pragma unroll
    for (int kk = 0; kk < 2; ++kk) {
      bf16x8 pa[2];
#pragma unroll
      for (int qh = 0; qh < 2; ++qh)
        pa[qh] = ld_frag(&Pw[((kk * 4 + quad) * 32 + qh * 16 + l15) * 8]);
#pragma unroll
      for (int j = 0; j < 4; ++j) {
        bf16x8 vb = ld_frag(&Vsm[cur][((kk * 4 + quad) * 64 + j * 16 + l15) * 8]);
#pragma unroll
        for (int qh = 0; qh < 2; ++qh)
          o[qh][j] = MFMA16(vb, pa[qh], o[qh][j]);
      }
    }
  }

  float inv[2];
#pragma unroll
  for (int qh = 0; qh < 2; ++qh) {
    ls[qh] += __shfl_xor(ls[qh], 16, 64);
    ls[qh] += __shfl_xor(ls[qh], 32, 64);
    inv[qh] = 1.f / ls[qh];
  }

  // O^T: row = d = j*16+quad*4+r, col = q = l15 -> 8B vector ctx stores
#pragma unroll
  for (int qh = 0; qh < 2; ++qh) {
    const int tok = b * 2048 + q0 + qh * 16 + l15;
#pragma unroll
    for (int j = 0; j < 4; ++j) {
      u16x4 pk;
#pragma unroll
      for (int r = 0; r < 4; ++r) pk[r] = cvt_bf(o[qh][j][r] * inv[qh]);
      *(u16x4*)&ctx[(size_t)tok * 1024 + h * 64 + j * 16 + quad * 4] = pk;
    }
  }
}

// ---------------------------------------------------------------------------
extern "C" void kernel_launch(void* const* d_in, const int* in_sizes, int n_in,
                              void* d_out, int out_size, void* d_ws, size_t ws_size,
                              hipStream_t stream) {
  const float* query = (const float*)d_in[0];
  const float* key   = (const float*)d_in[1];
  const float* value = (const float*)d_in[2];
  const float* Wq = (const float*)d_in[3];
  const float* Wk = (const float*)d_in[4];
  const float* Wv = (const float*)d_in[5];
  const float* Wo = (const float*)d_in[6];
  float* outp = (float*)d_out;

  // ws (u16 units): Wt 4Mi | Awq 8Mi | Qw 8Mi | Kw 8Mi | Vt 8Mi = 72 MB.
  // Awk/Awv live in d_out (32 MB, consumed before gemm_out overwrites it);
  // ctx aliases Awq (consumed by gemm_fwd before attn writes it).
  u16* Wt  = (u16*)d_ws;
  u16* Awq = Wt + ((size_t)4 << 20);
  u16* Qw  = Awq + ((size_t)8 << 20);
  u16* Kw  = Qw + ((size_t)8 << 20);
  u16* Vt  = Kw + ((size_t)8 << 20);
  u16* Awk = (u16*)d_out;
  u16* Awv = Awk + ((size_t)8 << 20);
  u16* Cw  = Awq;

  prep_w<<<dim3(16, 16, 4), 256, 0, stream>>>(Wq, Wk, Wv, Wo, Wt);
  prep_a<<<dim3(1024, 1, 3), 256, 0, stream>>>(query, key, value, Awq, Awk, Awv);
  gemm_fwd<<<dim3(8, 64, 3), 256, 0, stream>>>(Awq, Awk, Awv, Wt, Qw, Kw, Vt);
  attn<<<dim3(64, 16), 256, 0, stream>>>(Qw, Kw, Vt, Cw);
  gemm_out<<<dim3(8, 64), 256, 0, stream>>>(Cw, Wt + ((size_t)3 << 20), outp);
}